// Round 2
// baseline (395.671 us; speedup 1.0000x reference)
//
#include <hip/hip_runtime.h>
#include <hip/hip_bf16.h>

#define IN_CH 128
#define NEG_SLOPE 0.2f

// out[n*32+d] init = mean_h bias[h*32+d]
__global__ void k_init_out(const float* __restrict__ bias, float* __restrict__ out, int n32) {
    int i = blockIdx.x * 256 + threadIdx.x;
    if (i >= n32) return;
    int d = i & 31;
    out[i] = 0.25f * (bias[d] + bias[32 + d] + bias[64 + d] + bias[96 + d]);
}

// feat[N,128] = x[N,128] @ W[128,128], fp32 vector-ALU GEMM.
// W staged in LDS (64KB). Each thread: 2 rows x 4 cols. Block 256 -> 16 rows.
// grid = N/16 = 3125 (exact).
__global__ __launch_bounds__(256) void k_gemm(const float* __restrict__ x,
                                              const float* __restrict__ W,
                                              float* __restrict__ feat) {
    __shared__ float Wl[128 * 128];
#pragma unroll
    for (int i = 0; i < 16; ++i) {
        ((float4*)Wl)[threadIdx.x + 256 * i] = ((const float4*)W)[threadIdx.x + 256 * i];
    }
    __syncthreads();
    int grp = threadIdx.x >> 5;            // 0..7
    int c4 = (threadIdx.x & 31) * 4;       // col base
    int r0 = blockIdx.x * 16 + grp * 2;    // two rows: r0, r0+1
    const float* xa = x + (size_t)r0 * 128;
    const float* xb = xa + 128;
    float4 acc0 = {0.f, 0.f, 0.f, 0.f};
    float4 acc1 = {0.f, 0.f, 0.f, 0.f};
    for (int k8 = 0; k8 < 128; k8 += 8) {
        float4 a0 = *(const float4*)(xa + k8);
        float4 a1 = *(const float4*)(xa + k8 + 4);
        float4 b0 = *(const float4*)(xb + k8);
        float4 b1 = *(const float4*)(xb + k8 + 4);
        float av[8] = {a0.x, a0.y, a0.z, a0.w, a1.x, a1.y, a1.z, a1.w};
        float bv[8] = {b0.x, b0.y, b0.z, b0.w, b1.x, b1.y, b1.z, b1.w};
#pragma unroll
        for (int j = 0; j < 8; ++j) {
            float4 wv = *(const float4*)(Wl + (k8 + j) * 128 + c4);
            acc0.x += av[j] * wv.x; acc0.y += av[j] * wv.y;
            acc0.z += av[j] * wv.z; acc0.w += av[j] * wv.w;
            acc1.x += bv[j] * wv.x; acc1.y += bv[j] * wv.y;
            acc1.z += bv[j] * wv.z; acc1.w += bv[j] * wv.w;
        }
    }
    *(float4*)(feat + (size_t)r0 * 128 + c4) = acc0;
    *(float4*)(feat + (size_t)(r0 + 1) * 128 + c4) = acc1;
}

// el[n,h] = feat[n,h,:] . attn_l[h,:] ; er likewise. One thread per (n,h).
__global__ void k_elr(const float* __restrict__ feat,
                      const float* __restrict__ attn_l,
                      const float* __restrict__ attn_r,
                      float* __restrict__ el, float* __restrict__ er, int n4) {
    int idx = blockIdx.x * 256 + threadIdx.x;
    if (idx >= n4) return;
    int n = idx >> 2, h = idx & 3;
    const float4* f4 = (const float4*)(feat + (size_t)n * 128 + h * 32);
    const float4* al = (const float4*)(attn_l + h * 32);
    const float4* ar = (const float4*)(attn_r + h * 32);
    float sl = 0.f, sr = 0.f;
#pragma unroll
    for (int j = 0; j < 8; ++j) {
        float4 fv = f4[j];
        float4 lv = al[j];
        float4 rv = ar[j];
        sl += fv.x * lv.x + fv.y * lv.y + fv.z * lv.z + fv.w * lv.w;
        sr += fv.x * rv.x + fv.y * rv.y + fv.z * rv.z + fv.w * rv.w;
    }
    el[idx] = sl;
    er[idx] = sr;
}

// Pass A: ex[e,h] = exp(leaky_relu(el[src]+er[dst])); s[dst,h] += ex
// (softmax max-shift skipped: shift-invariant, logits are O(5) so no overflow)
__global__ void k_edgeA(const int* __restrict__ src, const int* __restrict__ dst,
                        const float* __restrict__ el, const float* __restrict__ er,
                        float* __restrict__ ex, float* __restrict__ s, int E) {
    int e = blockIdx.x * 256 + threadIdx.x;
    if (e >= E) return;
    int sn = src[e], dn = dst[e];
    float4 l = *(const float4*)(el + (size_t)sn * 4);
    float4 r = *(const float4*)(er + (size_t)dn * 4);
    float4 v;
    float t;
    t = l.x + r.x; v.x = __expf(t > 0.f ? t : NEG_SLOPE * t);
    t = l.y + r.y; v.y = __expf(t > 0.f ? t : NEG_SLOPE * t);
    t = l.z + r.z; v.z = __expf(t > 0.f ? t : NEG_SLOPE * t);
    t = l.w + r.w; v.w = __expf(t > 0.f ? t : NEG_SLOPE * t);
    *(float4*)(ex + (size_t)e * 4) = v;
    atomicAdd(&s[dn * 4 + 0], v.x);
    atomicAdd(&s[dn * 4 + 1], v.y);
    atomicAdd(&s[dn * 4 + 2], v.z);
    atomicAdd(&s[dn * 4 + 3], v.w);
}

// s -> 1/s in place (empty nodes give inf, never read).
__global__ void k_sinv(float* __restrict__ s, int n4) {
    int i = blockIdx.x * 256 + threadIdx.x;
    if (i >= n4) return;
    s[i] = 1.0f / s[i];
}

// Pass B: 32 lanes per edge; lane d computes sum_h 0.25*alpha_h*feat[src,h,d]
// -> one fp32 atomic per (edge, d) directly into d_out.
__global__ void k_edgeB(const int* __restrict__ src, const int* __restrict__ dst,
                        const float* __restrict__ ex, const float* __restrict__ sinv,
                        const float* __restrict__ feat, float* __restrict__ out, int E) {
    int t = blockIdx.x * 256 + threadIdx.x;
    int e = t >> 5;
    int d = t & 31;
    if (e >= E) return;
    int sn = src[e], dn = dst[e];
    float4 x4 = *(const float4*)(ex + (size_t)e * 4);
    float4 s4 = *(const float4*)(sinv + (size_t)dn * 4);
    float a0 = 0.25f * x4.x * s4.x;
    float a1 = 0.25f * x4.y * s4.y;
    float a2 = 0.25f * x4.z * s4.z;
    float a3 = 0.25f * x4.w * s4.w;
    const float* f = feat + (size_t)sn * 128;
    float v = a0 * f[d] + a1 * f[32 + d] + a2 * f[64 + d] + a3 * f[96 + d];
    atomicAdd(&out[(size_t)dn * 32 + d], v);
}

extern "C" void kernel_launch(void* const* d_in, const int* in_sizes, int n_in,
                              void* d_out, int out_size, void* d_ws, size_t ws_size,
                              hipStream_t stream) {
    const float* x      = (const float*)d_in[0];
    const int*   src    = (const int*)d_in[1];
    const int*   dst    = (const int*)d_in[2];
    const float* W      = (const float*)d_in[3];
    const float* attn_l = (const float*)d_in[4];
    const float* attn_r = (const float*)d_in[5];
    const float* bias   = (const float*)d_in[6];
    float* out = (float*)d_out;

    int N = in_sizes[0] / IN_CH;   // 50000
    int E = in_sizes[1];           // 800000

    char* w = (char*)d_ws;
    float* feat = (float*)w;  w += (size_t)N * 128 * 4;   // 25.6 MB
    float* el   = (float*)w;  w += (size_t)N * 4 * 4;     //  0.8 MB
    float* er   = (float*)w;  w += (size_t)N * 4 * 4;     //  0.8 MB
    float* s    = (float*)w;  w += (size_t)N * 4 * 4;     //  0.8 MB
    float* ex   = (float*)w;  w += (size_t)E * 4 * 4;     // 12.8 MB

    hipMemsetAsync(s, 0, (size_t)N * 4 * 4, stream);
    k_init_out<<<(N * 32 + 255) / 256, 256, 0, stream>>>(bias, out, N * 32);
    k_gemm<<<N / 16, 256, 0, stream>>>(x, W, feat);
    k_elr<<<(N * 4 + 255) / 256, 256, 0, stream>>>(feat, attn_l, attn_r, el, er, N * 4);
    k_edgeA<<<(E + 255) / 256, 256, 0, stream>>>(src, dst, el, er, ex, s, E);
    k_sinv<<<(N * 4 + 255) / 256, 256, 0, stream>>>(s, N * 4);
    k_edgeB<<<(int)(((size_t)E * 32 + 255) / 256), 256, 0, stream>>>(src, dst, ex, s, feat, out, E);
}